// Round 11
// baseline (319.805 us; speedup 1.0000x reference)
//
#include <hip/hip_runtime.h>
#include <math.h>

// Problem constants
#define B_ 8
#define N_ 5000
#define E_ 160000
#define M_ 40000      // N_*B_ rows, r = n*B_ + b
#define K_ 512
#define XT_ 313       // (M_+127)/128 row tiles
#define CAP_ 128      // fixed per-node CSR capacity (mean deg 32, max ~58)

typedef __bf16 v8bf __attribute__((ext_vector_type(8)));
typedef float  v4f  __attribute__((ext_vector_type(4)));
typedef unsigned short u16x4v __attribute__((ext_vector_type(4)));
typedef unsigned short u16x8v __attribute__((ext_vector_type(8)));

__device__ __forceinline__ unsigned short f2b(float f){
  unsigned int u = __builtin_bit_cast(unsigned int, f);
  u += 0x7FFFu + ((u >> 16) & 1u);          // round-to-nearest-even
  return (unsigned short)(u >> 16);
}
__device__ __forceinline__ float b2f(unsigned short s){
  return __builtin_bit_cast(float, ((unsigned int)s) << 16);
}
__device__ __forceinline__ float softplus_(float x){
  return (x > 15.0f) ? x : __logf(1.0f + __expf(x));
}
__device__ __forceinline__ float tanh_(float x){
  float e = __expf(2.0f*x);
  return 1.0f - 2.0f/(e + 1.0f);
}

// ---------------- prep: zero cursor + convert weights + convert u (fused) --------
// blockIdx ranges: [0,10000) convert_u, [10000,12564) convert_weights,
// [12564,12584) zero cursor.
__global__ __launch_bounds__(256) void prep_kernel(
    const float* __restrict__ u,
    const float* __restrict__ wA, const float* __restrict__ wFc,
    const float* __restrict__ wGc, const float* __restrict__ wZ,
    const float* __restrict__ wFh,
    const float* __restrict__ bFc, const float* __restrict__ bGc,
    const float* __restrict__ bZ,  const float* __restrict__ bFh,
    unsigned short* __restrict__ cB, unsigned short* __restrict__ hT,
    unsigned short* __restrict__ WA, unsigned short* __restrict__ Wall,
    float* __restrict__ biasP, int* __restrict__ cursor)
{
  const int bid = blockIdx.x;
  if (bid < 10000){
    // convert_u, widened: wave = 1 row; lanes 0-31 -> c cols li*8, lanes 32-63 ->
    // h cols li*8. 32B/lane reads, one 16B packed write/lane (was 2x 8B).
    const int r = bid*4 + (threadIdx.x >> 6);
    const int l = threadIdx.x & 63;
    const int half = l >> 5, li = l & 31;
    const int n = r >> 3, b = r & 7;
    const float* up = u + (size_t)(b*N_ + n)*512 + half*256 + li*8;
    float4 f0 = *(const float4*)up;
    float4 f1 = *(const float4*)(up + 4);
    u16x8v o;
    o[0] = f2b(f0.x); o[1] = f2b(f0.y); o[2] = f2b(f0.z); o[3] = f2b(f0.w);
    o[4] = f2b(f1.x); o[5] = f2b(f1.y); o[6] = f2b(f1.z); o[7] = f2b(f1.w);
    unsigned short* dstp = half ? hT : cB;
    *(u16x8v*)(dstp + (size_t)r*256 + li*8) = o;
    return;
  }
  if (bid < 12564){
    // convert_weights -> fragment-packed B layout + packed bias.
    int idx = (bid - 10000)*256 + threadIdx.x;   // < 656384
    if (idx >= 655360){
      int j = idx - 655360;                      // 0..1023
      int mat = j >> 8, jj = j & 255;
      const float* bp = (mat == 0) ? bFc : (mat == 1) ? bGc : (mat == 2) ? bZ : bFh;
      biasP[j] = bp[jj];
      return;
    }
    int m = idx >> 17;
    int i = idx & 131071;
    float v;
    if      (m == 0) v = wA[i];
    else if (m == 1) v = wFc[i];
    else if (m == 2) v = wGc[i];
    else if (m == 3) v = wZ[i];
    else             v = wFh[i];
    unsigned short o = f2b(v);
    int n   = (m == 0) ? (i >> 9) : ((m - 1)*256 + (i >> 9));
    int col = i & 511;
    int y  = n >> 7, nn = n & 127;
    int cb = nn >> 4, lr = nn & 15;
    int kb = col >> 6, c6 = col & 63;
    int ch = c6 >> 3, e = c6 & 7;
    int ks = ch >> 2, lq = ch & 3;
    int lane = lq*16 + lr;
    size_t pidx = ((((size_t)(y*8 + kb)*2 + ks)*8 + cb)*64 + lane)*8 + e;
    if (m == 0) WA[pidx] = o;
    else        Wall[pidx] = o;
    return;
  }
  // zero cursor
  int i = (bid - 12564)*256 + threadIdx.x;
  if (i < N_) cursor[i] = 0;
}

// ---------------- fill_direct: one-kernel CSR ----------------
__global__ __launch_bounds__(256) void fill_direct(
    const int* __restrict__ src, const int* __restrict__ dst,
    int* __restrict__ cursor, int* __restrict__ csr)
{
  int e = blockIdx.x*256 + threadIdx.x;
  int d = dst[e];
  int p = atomicAdd(&cursor[d], 1);
  if (p < CAP_) csr[d*CAP_ + p] = src[e];
}

// ---------------- gather: batch-partitioned across XCDs ----------------
__global__ __launch_bounds__(256) void gather_bn_kernel(
    const unsigned short* __restrict__ hT, const int* __restrict__ csr,
    const int* __restrict__ cursor, unsigned short* __restrict__ aggT)
{
  const int id = blockIdx.x;
  const int bb = id & 7;
  const int g  = id >> 3;
  const int tid = threadIdx.x;
  const int n = g*4 + (tid >> 6);
  const int l = tid & 63;
  const int half = l >> 5, li = l & 31;
  const size_t coff = (size_t)bb*256 + li*8;
  const int cnt = min(cursor[n], CAP_);
  const int base = n*CAP_;

  float acc[8] = {};
  int e = 0;
  for (; e + 3 < cnt; e += 4){
    const int s0 = csr[base + e + half];
    const int s1 = csr[base + e + 2 + half];
    u16x8v v0 = *(const u16x8v*)(hT + (size_t)s0*2048 + coff);
    u16x8v v1 = *(const u16x8v*)(hT + (size_t)s1*2048 + coff);
#pragma unroll
    for (int i = 0; i < 8; ++i) acc[i] += b2f(v0[i]) + b2f(v1[i]);
  }
  for (; e < cnt; e += 2){
    const int idx = e + half;
    u16x8v v = {};
    if (idx < cnt){
      const int s = csr[base + idx];
      v = *(const u16x8v*)(hT + (size_t)s*2048 + coff);
    }
#pragma unroll
    for (int i = 0; i < 8; ++i) acc[i] += b2f(v[i]);
  }
#pragma unroll
  for (int i = 0; i < 8; ++i) acc[i] += __shfl_xor(acc[i], 32, 64);

  if (half == 0){
    const float inv = 1.0f / (float)((cnt > 1) ? cnt : 1);
    u16x8v o;
#pragma unroll
    for (int i = 0; i < 8; ++i) o[i] = f2b(acc[i]*inv);
    *(u16x8v*)(aggT + (size_t)n*2048 + coff) = o;
  }
}

// ---------------- tiled GEMM (R5-exact schedule; MODE 1 defers activation) -------
// MODE 0: softplus in-kernel (output feeds gemm<1> as MFMA operand).
// MODE 1: stores RAW bf16(acc+bias); activation deferred to epilogue (R10 win).
// MODE 1 grid is SPLIT into two launches (y0 = 0 / 4) this round so the
// sub-gemm kernels surface in the top-5 profile table (visibility round).
// Decode keeps the same-XCD x-grouping (id&7 = x-subindex in both modes).

__device__ __forceinline__ void stage_a(
    const unsigned short* __restrict__ As, int m0, int ak,
    int srow, int schunk, int w, unsigned short* lbuf)
{
#pragma unroll
  for (int i = 0; i < 4; ++i){
    const unsigned short* gp = As + (size_t)(m0 + i*32 + srow)*256 + ak + schunk*8;
    unsigned short* lp = lbuf + (i*32 + w*8)*64;
    __builtin_amdgcn_global_load_lds((const __attribute__((address_space(1))) void*)gp,
                                     (__attribute__((address_space(3))) void*)lp, 16, 0, 0);
  }
}

__device__ __forceinline__ void load_b(
    const unsigned short* __restrict__ Bp, int y, int kb, int wc, int l, v8bf (&b)[8])
{
#pragma unroll
  for (int ks = 0; ks < 2; ++ks)
#pragma unroll
    for (int ct = 0; ct < 4; ++ct)
      b[ks*4+ct] = *(const v8bf*)(Bp +
          ((((size_t)(y*8 + kb)*2 + ks)*8 + wc*4 + ct)*64 + l)*8);
}

__device__ __forceinline__ void compute_tile(
    const unsigned short* lA, int wr, int lq, int lr,
    const v8bf (&bb)[8], v4f (&acc)[4][4])
{
#pragma unroll
  for (int ks = 0; ks < 2; ++ks){
    v8bf a[4];
#pragma unroll
    for (int rt = 0; rt < 4; ++rt){
      const int ar = wr*64 + rt*16 + lr;
      a[rt] = *(const v8bf*)(lA + ar*64 + (((ks*4 + lq) ^ (ar & 7)))*8);
    }
#pragma unroll
    for (int rt = 0; rt < 4; ++rt)
#pragma unroll
      for (int ct = 0; ct < 4; ++ct)
        acc[rt][ct] = __builtin_amdgcn_mfma_f32_16x16x32_bf16(a[rt], bb[ks*4+ct], acc[rt][ct], 0, 0, 0);
  }
}

template<int MODE>
__global__ __launch_bounds__(256, 3) void gemm_tiled(
    const unsigned short* __restrict__ A0, const unsigned short* __restrict__ A1,
    const unsigned short* __restrict__ Bp, const float* __restrict__ bias,
    unsigned short* dstp, int y0)
{
  const int id = blockIdx.x;
  int x, y;
  if (MODE == 1){
    const int u5 = id & 31;          // 4 y-slabs x 8 x-subs per 32-id window
    y = y0 + (u5 >> 3);
    x = (id >> 5)*8 + (id & 7);
  } else {
    const int u4 = id & 15;
    y = u4 >> 3;
    x = (id >> 4)*8 + (u4 & 7);
  }
  if (x >= XT_) return;

  __shared__ unsigned short lds[24576];   // 3 x 16KB staging; repack reuses

  const int tid = threadIdx.x;
  const int w  = tid >> 6, l = tid & 63;
  const int wr = w >> 1,  wc = w & 1;
  const int lq = l >> 4,  lr = l & 15;
  const int m0 = x * 128;
  const int n0 = y * 128;

  const int srow   = tid >> 3;
  const int schunk = (tid & 7) ^ (srow & 7);

  v4f acc[4][4] = {};
  v8bf b0[8], b1[8];

  stage_a(A0, m0, 0,  srow, schunk, w, lds);
  asm volatile("" ::: "memory");
  load_b(Bp, y, 0, wc, l, b0);
  asm volatile("" ::: "memory");
  stage_a(A0, m0, 64, srow, schunk, w, lds + 8192);
  asm volatile("s_waitcnt vmcnt(12)" ::: "memory");
  __builtin_amdgcn_s_barrier();
  __builtin_amdgcn_sched_barrier(0);

#pragma unroll
  for (int kb = 0; kb < 7; ++kb){
    const int kp = kb + 2;
    if (kp < 8)
      stage_a((kp < 4) ? A0 : A1, m0, (kp & 3)*64, srow, schunk, w,
              lds + (kp % 3)*8192);
    asm volatile("" ::: "memory");
    if ((kb + 1) & 1) load_b(Bp, y, kb + 1, wc, l, b1);
    else              load_b(Bp, y, kb + 1, wc, l, b0);
    if (kb & 1) compute_tile(lds + (kb % 3)*8192, wr, lq, lr, b1, acc);
    else        compute_tile(lds + (kb % 3)*8192, wr, lq, lr, b0, acc);
    asm volatile("s_waitcnt vmcnt(12)" ::: "memory");
    __builtin_amdgcn_s_barrier();
    __builtin_amdgcn_sched_barrier(0);
  }
  compute_tile(lds + 8192, wr, lq, lr, b1, acc);   // kb=7: buf 7%3=1, b1

  float bv[4];
#pragma unroll
  for (int ct = 0; ct < 4; ++ct) bv[ct] = bias[n0 + wc*64 + ct*16 + lr];

  __syncthreads();   // done reading lds; reuse as output repack buffer
#pragma unroll
  for (int rt = 0; rt < 4; ++rt){
#pragma unroll
    for (int ct = 0; ct < 4; ++ct){
      const int col = wc*64 + ct*16 + lr;
#pragma unroll
      for (int reg = 0; reg < 4; ++reg){
        const int row = wr*64 + rt*16 + lq*4 + reg;
        const float xv = acc[rt][ct][reg] + bv[ct];
        const float v = (MODE == 0) ? softplus_(xv) : xv;   // MODE 1: raw
        lds[row*136 + col] = f2b(v);
      }
    }
  }
  __syncthreads();

#pragma unroll
  for (int i = 0; i < 8; ++i){
    const int row = i*16 + (tid >> 4);
    const int r = m0 + row;
    if (r < M_){
      const uint4 v = *(const uint4*)(lds + row*136 + (tid & 15)*8);
      if (MODE == 0){
        *(uint4*)(dstp + (size_t)r*256 + n0 + (tid & 15)*8) = v;
      } else {
        const int n = r >> 3, b = r & 7;
        *(uint4*)(dstp + ((size_t)b*N_ + n)*1024 + n0 + (tid & 15)*8) = v;
      }
    }
  }
}

// ---------------- epilogue: deferred activations + dc projection + dh ------------
// Widened: wave = 2 rows (half-wave per row), lane covers 8 cols -> all act
// loads 16B u16x8v (were 8B), u reads 32B/lane, stores 32B/lane. Shuffle
// reduce stays within each 32-lane half (masks 1..16 preserve bit 5).
__global__ __launch_bounds__(256) void epilogue_kernel(
    const unsigned short* act, const float* __restrict__ u, float* out)
{
  const int tid = threadIdx.x;
  const int w = tid >> 6, l = tid & 63;
  const int half = l >> 5, li = l & 31;
  const int r = blockIdx.x*8 + w*2 + half;
  const int n = r >> 3, b = r & 7;
  const size_t rr = (size_t)(b*N_ + n);
  const unsigned short* arow = act + rr*1024;
  const float* urow = u + rr*512;
  float* orow = out + rr*512;
  const int q0 = li*8;

  u16x8v fc8 = *(const u16x8v*)(arow +        q0);
  u16x8v gc8 = *(const u16x8v*)(arow + 256 +  q0);
  u16x8v z8  = *(const u16x8v*)(arow + 512 +  q0);
  u16x8v fh8 = *(const u16x8v*)(arow + 768 +  q0);
  float4 c4a = *(const float4*)(urow + q0);
  float4 c4b = *(const float4*)(urow + q0 + 4);
  float4 h4a = *(const float4*)(urow + 256 + q0);
  float4 h4b = *(const float4*)(urow + 256 + q0 + 4);

  float c[8] = {c4a.x,c4a.y,c4a.z,c4a.w,c4b.x,c4b.y,c4b.z,c4b.w};
  float h[8] = {h4a.x,h4a.y,h4a.z,h4a.w,h4b.x,h4b.y,h4b.z,h4b.w};
  float dc[8], fh[8];
  float num = 0.f, den = 0.f;
#pragma unroll
  for (int i = 0; i < 8; ++i){
    float fc = softplus_(b2f(fc8[i]));
    float gc = softplus_(b2f(gc8[i]));
    float z  = tanh_(b2f(z8[i]));
    fh[i] = softplus_(b2f(fh8[i]));
    dc[i] = -fc*c[i] + gc*z;
    num += dc[i]*c[i];
    den += c[i]*c[i];
  }
#pragma unroll
  for (int s = 1; s < 32; s <<= 1){
    num += __shfl_xor(num, s, 64);
    den += __shfl_xor(den, s, 64);
  }
  const float proj = num / den;

  float4 oa, ob, ha, hb;
  oa.x = dc[0]-proj*c[0]; oa.y = dc[1]-proj*c[1]; oa.z = dc[2]-proj*c[2]; oa.w = dc[3]-proj*c[3];
  ob.x = dc[4]-proj*c[4]; ob.y = dc[5]-proj*c[5]; ob.z = dc[6]-proj*c[6]; ob.w = dc[7]-proj*c[7];
  ha.x = -fh[0]*h[0]; ha.y = -fh[1]*h[1]; ha.z = -fh[2]*h[2]; ha.w = -fh[3]*h[3];
  hb.x = -fh[4]*h[4]; hb.y = -fh[5]*h[5]; hb.z = -fh[6]*h[6]; hb.w = -fh[7]*h[7];
  *(float4*)(orow + q0)       = oa;
  *(float4*)(orow + q0 + 4)   = ob;
  *(float4*)(orow + 256 + q0)     = ha;
  *(float4*)(orow + 256 + q0 + 4) = hb;
}

// ---------------- launch ----------------

extern "C" void kernel_launch(void* const* d_in, const int* in_sizes, int n_in,
                              void* d_out, int out_size, void* d_ws, size_t ws_size,
                              hipStream_t stream) {
  const float* u    = (const float*)d_in[0];
  const int*   src  = (const int*)d_in[1];
  const int*   dst  = (const int*)d_in[2];
  const float* wFc  = (const float*)d_in[4];
  const float* bFc  = (const float*)d_in[5];
  const float* wFh  = (const float*)d_in[6];
  const float* bFh  = (const float*)d_in[7];
  const float* wGc  = (const float*)d_in[8];
  const float* bGc  = (const float*)d_in[9];
  const float* wZ   = (const float*)d_in[10];
  const float* bZ   = (const float*)d_in[11];
  const float* wA   = (const float*)d_in[12];
  const float* bA   = (const float*)d_in[13];
  float* out = (float*)d_out;
  unsigned short* act = (unsigned short*)d_out;   // bf16 activations overlay out

  // ws layout. GEMM A-staging over-reads up to 64 rows past hT/cB/aggT/hB ends —
  // overflow lands in the NEXT allocation (readable garbage, discarded by the
  // r < M_ guard). csr (2.56 MB) ALIASES the hB region: csr is live only
  // fill_direct -> gather; hB is written by gemm<0> strictly after gather.
  char* W = (char*)d_ws;
  unsigned short* hT   = (unsigned short*)(W + 0);           // 20,480,000 B
  unsigned short* cB   = (unsigned short*)(W + 20480000);
  unsigned short* aggT = (unsigned short*)(W + 40960000);
  unsigned short* hB   = (unsigned short*)(W + 61440000);    // 20,480,000 B
  int* csr             = (int*)(W + 61440000);               // 2,560,000 B (aliased)
  unsigned short* WA   = (unsigned short*)(W + 81920000);    // 262,144 B (packed)
  unsigned short* Wall = (unsigned short*)(W + 82182144);    // 1,048,576 B (packed)
  float* biasP   = (float*)(W + 83230720);                   // 4,096 B
  int* cursor    = (int*)(W + 83234816);                     // 20,480 B

  // 7-kernel pipeline (gemm<1> split 2x for top-5 visibility this round)
  prep_kernel<<<12584, 256, 0, stream>>>(u, wA, wFc, wGc, wZ, wFh,
                                         bFc, bGc, bZ, bFh,
                                         cB, hT, WA, Wall, biasP, cursor);
  fill_direct<<<E_/256, 256, 0, stream>>>(src, dst, cursor, csr);
  gather_bn_kernel<<<8*1250, 256, 0, stream>>>(hT, csr, cursor, aggT);

  gemm_tiled<0><<<40*16, 256, 0, stream>>>(hT, aggT, WA, bA, hB, 0);
  gemm_tiled<1><<<40*32, 256, 0, stream>>>(cB, hB, Wall, biasP, act, 0);
  gemm_tiled<1><<<40*32, 256, 0, stream>>>(cB, hB, Wall, biasP, act, 4);

  epilogue_kernel<<<M_/8, 256, 0, stream>>>(act, u, out);
}

// Round 12
// 313.665 us; speedup vs baseline: 1.0196x; 1.0196x over previous
//
#include <hip/hip_runtime.h>
#include <math.h>

// Problem constants
#define B_ 8
#define N_ 5000
#define E_ 160000
#define M_ 40000      // N_*B_ rows, r = n*B_ + b
#define K_ 512
#define XT_ 313       // (M_+127)/128 row tiles
#define CAP_ 128      // fixed per-node CSR capacity (mean deg 32, max ~58)

typedef __bf16 v8bf __attribute__((ext_vector_type(8)));
typedef float  v4f  __attribute__((ext_vector_type(4)));
typedef unsigned short u16x4v __attribute__((ext_vector_type(4)));
typedef unsigned short u16x8v __attribute__((ext_vector_type(8)));

__device__ __forceinline__ unsigned short f2b(float f){
  unsigned int u = __builtin_bit_cast(unsigned int, f);
  u += 0x7FFFu + ((u >> 16) & 1u);          // round-to-nearest-even
  return (unsigned short)(u >> 16);
}
__device__ __forceinline__ float b2f(unsigned short s){
  return __builtin_bit_cast(float, ((unsigned int)s) << 16);
}
__device__ __forceinline__ float softplus_(float x){
  return (x > 15.0f) ? x : __logf(1.0f + __expf(x));
}
__device__ __forceinline__ float tanh_(float x){
  float e = __expf(2.0f*x);
  return 1.0f - 2.0f/(e + 1.0f);
}

// ---------------- prep: zero cursor + convert weights + convert u (fused) --------
// blockIdx ranges: [0,10000) convert_u, [10000,12564) convert_weights,
// [12564,12584) zero cursor.
__global__ __launch_bounds__(256) void prep_kernel(
    const float* __restrict__ u,
    const float* __restrict__ wA, const float* __restrict__ wFc,
    const float* __restrict__ wGc, const float* __restrict__ wZ,
    const float* __restrict__ wFh,
    const float* __restrict__ bFc, const float* __restrict__ bGc,
    const float* __restrict__ bZ,  const float* __restrict__ bFh,
    unsigned short* __restrict__ cB, unsigned short* __restrict__ hT,
    unsigned short* __restrict__ WA, unsigned short* __restrict__ Wall,
    float* __restrict__ biasP, int* __restrict__ cursor)
{
  const int bid = blockIdx.x;
  if (bid < 10000){
    // convert_u, widened: wave = 1 row; lanes 0-31 -> c cols li*8, lanes 32-63 ->
    // h cols li*8. 32B/lane reads, one 16B packed write/lane.
    const int r = bid*4 + (threadIdx.x >> 6);
    const int l = threadIdx.x & 63;
    const int half = l >> 5, li = l & 31;
    const int n = r >> 3, b = r & 7;
    const float* up = u + (size_t)(b*N_ + n)*512 + half*256 + li*8;
    float4 f0 = *(const float4*)up;
    float4 f1 = *(const float4*)(up + 4);
    u16x8v o;
    o[0] = f2b(f0.x); o[1] = f2b(f0.y); o[2] = f2b(f0.z); o[3] = f2b(f0.w);
    o[4] = f2b(f1.x); o[5] = f2b(f1.y); o[6] = f2b(f1.z); o[7] = f2b(f1.w);
    unsigned short* dstp = half ? hT : cB;
    *(u16x8v*)(dstp + (size_t)r*256 + li*8) = o;
    return;
  }
  if (bid < 12564){
    // convert_weights -> fragment-packed B layout + packed bias.
    int idx = (bid - 10000)*256 + threadIdx.x;   // < 656384
    if (idx >= 655360){
      int j = idx - 655360;                      // 0..1023
      int mat = j >> 8, jj = j & 255;
      const float* bp = (mat == 0) ? bFc : (mat == 1) ? bGc : (mat == 2) ? bZ : bFh;
      biasP[j] = bp[jj];
      return;
    }
    int m = idx >> 17;
    int i = idx & 131071;
    float v;
    if      (m == 0) v = wA[i];
    else if (m == 1) v = wFc[i];
    else if (m == 2) v = wGc[i];
    else if (m == 3) v = wZ[i];
    else             v = wFh[i];
    unsigned short o = f2b(v);
    int n   = (m == 0) ? (i >> 9) : ((m - 1)*256 + (i >> 9));
    int col = i & 511;
    int y  = n >> 7, nn = n & 127;
    int cb = nn >> 4, lr = nn & 15;
    int kb = col >> 6, c6 = col & 63;
    int ch = c6 >> 3, e = c6 & 7;
    int ks = ch >> 2, lq = ch & 3;
    int lane = lq*16 + lr;
    size_t pidx = ((((size_t)(y*8 + kb)*2 + ks)*8 + cb)*64 + lane)*8 + e;
    if (m == 0) WA[pidx] = o;
    else        Wall[pidx] = o;
    return;
  }
  // zero cursor
  int i = (bid - 12564)*256 + threadIdx.x;
  if (i < N_) cursor[i] = 0;
}

// ---------------- fill_direct: one-kernel CSR ----------------
__global__ __launch_bounds__(256) void fill_direct(
    const int* __restrict__ src, const int* __restrict__ dst,
    int* __restrict__ cursor, int* __restrict__ csr)
{
  int e = blockIdx.x*256 + threadIdx.x;
  int d = dst[e];
  int p = atomicAdd(&cursor[d], 1);
  if (p < CAP_) csr[d*CAP_ + p] = src[e];
}

// ---------------- gather: batch-partitioned across XCDs ----------------
__global__ __launch_bounds__(256) void gather_bn_kernel(
    const unsigned short* __restrict__ hT, const int* __restrict__ csr,
    const int* __restrict__ cursor, unsigned short* __restrict__ aggT)
{
  const int id = blockIdx.x;
  const int bb = id & 7;
  const int g  = id >> 3;
  const int tid = threadIdx.x;
  const int n = g*4 + (tid >> 6);
  const int l = tid & 63;
  const int half = l >> 5, li = l & 31;
  const size_t coff = (size_t)bb*256 + li*8;
  const int cnt = min(cursor[n], CAP_);
  const int base = n*CAP_;

  float acc[8] = {};
  int e = 0;
  for (; e + 3 < cnt; e += 4){
    const int s0 = csr[base + e + half];
    const int s1 = csr[base + e + 2 + half];
    u16x8v v0 = *(const u16x8v*)(hT + (size_t)s0*2048 + coff);
    u16x8v v1 = *(const u16x8v*)(hT + (size_t)s1*2048 + coff);
#pragma unroll
    for (int i = 0; i < 8; ++i) acc[i] += b2f(v0[i]) + b2f(v1[i]);
  }
  for (; e < cnt; e += 2){
    const int idx = e + half;
    u16x8v v = {};
    if (idx < cnt){
      const int s = csr[base + idx];
      v = *(const u16x8v*)(hT + (size_t)s*2048 + coff);
    }
#pragma unroll
    for (int i = 0; i < 8; ++i) acc[i] += b2f(v[i]);
  }
#pragma unroll
  for (int i = 0; i < 8; ++i) acc[i] += __shfl_xor(acc[i], 32, 64);

  if (half == 0){
    const float inv = 1.0f / (float)((cnt > 1) ? cnt : 1);
    u16x8v o;
#pragma unroll
    for (int i = 0; i < 8; ++i) o[i] = f2b(acc[i]*inv);
    *(u16x8v*)(aggT + (size_t)n*2048 + coff) = o;
  }
}

// ---------------- tiled GEMM (R5-exact schedule; MODE 1 defers activation) -------
// MODE 0: softplus in-kernel (output feeds gemm<1> as MFMA operand).
// MODE 1: stores RAW bf16(acc+bias); activation deferred to epilogue (R10 win).
// Single MODE-1 launch again (R11 split was instrumentation; cost ~3 us).

__device__ __forceinline__ void stage_a(
    const unsigned short* __restrict__ As, int m0, int ak,
    int srow, int schunk, int w, unsigned short* lbuf)
{
#pragma unroll
  for (int i = 0; i < 4; ++i){
    const unsigned short* gp = As + (size_t)(m0 + i*32 + srow)*256 + ak + schunk*8;
    unsigned short* lp = lbuf + (i*32 + w*8)*64;
    __builtin_amdgcn_global_load_lds((const __attribute__((address_space(1))) void*)gp,
                                     (__attribute__((address_space(3))) void*)lp, 16, 0, 0);
  }
}

__device__ __forceinline__ void load_b(
    const unsigned short* __restrict__ Bp, int y, int kb, int wc, int l, v8bf (&b)[8])
{
#pragma unroll
  for (int ks = 0; ks < 2; ++ks)
#pragma unroll
    for (int ct = 0; ct < 4; ++ct)
      b[ks*4+ct] = *(const v8bf*)(Bp +
          ((((size_t)(y*8 + kb)*2 + ks)*8 + wc*4 + ct)*64 + l)*8);
}

__device__ __forceinline__ void compute_tile(
    const unsigned short* lA, int wr, int lq, int lr,
    const v8bf (&bb)[8], v4f (&acc)[4][4])
{
#pragma unroll
  for (int ks = 0; ks < 2; ++ks){
    v8bf a[4];
#pragma unroll
    for (int rt = 0; rt < 4; ++rt){
      const int ar = wr*64 + rt*16 + lr;
      a[rt] = *(const v8bf*)(lA + ar*64 + (((ks*4 + lq) ^ (ar & 7)))*8);
    }
#pragma unroll
    for (int rt = 0; rt < 4; ++rt)
#pragma unroll
      for (int ct = 0; ct < 4; ++ct)
        acc[rt][ct] = __builtin_amdgcn_mfma_f32_16x16x32_bf16(a[rt], bb[ks*4+ct], acc[rt][ct], 0, 0, 0);
  }
}

template<int MODE>
__global__ __launch_bounds__(256, 3) void gemm_tiled(
    const unsigned short* __restrict__ A0, const unsigned short* __restrict__ A1,
    const unsigned short* __restrict__ Bp, const float* __restrict__ bias,
    unsigned short* dstp)
{
  const int id = blockIdx.x;
  int x, y;
  if (MODE == 1){
    const int u6 = id & 63;
    y = u6 >> 3;
    x = (id >> 6)*8 + (u6 & 7);
  } else {
    const int u4 = id & 15;
    y = u4 >> 3;
    x = (id >> 4)*8 + (u4 & 7);
  }
  if (x >= XT_) return;

  __shared__ unsigned short lds[24576];   // 3 x 16KB staging; repack reuses

  const int tid = threadIdx.x;
  const int w  = tid >> 6, l = tid & 63;
  const int wr = w >> 1,  wc = w & 1;
  const int lq = l >> 4,  lr = l & 15;
  const int m0 = x * 128;
  const int n0 = y * 128;

  const int srow   = tid >> 3;
  const int schunk = (tid & 7) ^ (srow & 7);

  v4f acc[4][4] = {};
  v8bf b0[8], b1[8];

  stage_a(A0, m0, 0,  srow, schunk, w, lds);
  asm volatile("" ::: "memory");
  load_b(Bp, y, 0, wc, l, b0);
  asm volatile("" ::: "memory");
  stage_a(A0, m0, 64, srow, schunk, w, lds + 8192);
  asm volatile("s_waitcnt vmcnt(12)" ::: "memory");
  __builtin_amdgcn_s_barrier();
  __builtin_amdgcn_sched_barrier(0);

#pragma unroll
  for (int kb = 0; kb < 7; ++kb){
    const int kp = kb + 2;
    if (kp < 8)
      stage_a((kp < 4) ? A0 : A1, m0, (kp & 3)*64, srow, schunk, w,
              lds + (kp % 3)*8192);
    asm volatile("" ::: "memory");
    if ((kb + 1) & 1) load_b(Bp, y, kb + 1, wc, l, b1);
    else              load_b(Bp, y, kb + 1, wc, l, b0);
    if (kb & 1) compute_tile(lds + (kb % 3)*8192, wr, lq, lr, b1, acc);
    else        compute_tile(lds + (kb % 3)*8192, wr, lq, lr, b0, acc);
    asm volatile("s_waitcnt vmcnt(12)" ::: "memory");
    __builtin_amdgcn_s_barrier();
    __builtin_amdgcn_sched_barrier(0);
  }
  compute_tile(lds + 8192, wr, lq, lr, b1, acc);   // kb=7: buf 7%3=1, b1

  float bv[4];
#pragma unroll
  for (int ct = 0; ct < 4; ++ct) bv[ct] = bias[n0 + wc*64 + ct*16 + lr];

  __syncthreads();   // done reading lds; reuse as output repack buffer
#pragma unroll
  for (int rt = 0; rt < 4; ++rt){
#pragma unroll
    for (int ct = 0; ct < 4; ++ct){
      const int col = wc*64 + ct*16 + lr;
#pragma unroll
      for (int reg = 0; reg < 4; ++reg){
        const int row = wr*64 + rt*16 + lq*4 + reg;
        const float xv = acc[rt][ct][reg] + bv[ct];
        const float v = (MODE == 0) ? softplus_(xv) : xv;   // MODE 1: raw
        lds[row*136 + col] = f2b(v);
      }
    }
  }
  __syncthreads();

#pragma unroll
  for (int i = 0; i < 8; ++i){
    const int row = i*16 + (tid >> 4);
    const int r = m0 + row;
    if (r < M_){
      const uint4 v = *(const uint4*)(lds + row*136 + (tid & 15)*8);
      if (MODE == 0){
        *(uint4*)(dstp + (size_t)r*256 + n0 + (tid & 15)*8) = v;
      } else {
        const int n = r >> 3, b = r & 7;
        *(uint4*)(dstp + ((size_t)b*N_ + n)*1024 + n0 + (tid & 15)*8) = v;
      }
    }
  }
}

// ---------------- epilogue: deferred activations + dc projection + dh ------------
// Reads c,h from the bf16 mirrors cB/hT (41 MB) instead of fp32 u (82 MB):
// traffic 246 -> 205 MB. Wave = 2 rows (half-wave per row), 16B act loads,
// shuffle reduce within 32-lane halves.
__global__ __launch_bounds__(256) void epilogue_kernel(
    const unsigned short* act, const unsigned short* __restrict__ cB,
    const unsigned short* __restrict__ hT, float* out)
{
  const int tid = threadIdx.x;
  const int w = tid >> 6, l = tid & 63;
  const int half = l >> 5, li = l & 31;
  const int r = blockIdx.x*8 + w*2 + half;     // r = n*8 + b
  const int n = r >> 3, b = r & 7;
  const size_t rr = (size_t)(b*N_ + n);
  const unsigned short* arow = act + rr*1024;
  float* orow = out + rr*512;
  const int q0 = li*8;

  u16x8v fc8 = *(const u16x8v*)(arow +        q0);
  u16x8v gc8 = *(const u16x8v*)(arow + 256 +  q0);
  u16x8v z8  = *(const u16x8v*)(arow + 512 +  q0);
  u16x8v fh8 = *(const u16x8v*)(arow + 768 +  q0);
  u16x8v c8  = *(const u16x8v*)(cB + (size_t)r*256 + q0);
  u16x8v h8  = *(const u16x8v*)(hT + (size_t)r*256 + q0);

  float c[8], h[8], dc[8], fh[8];
  float num = 0.f, den = 0.f;
#pragma unroll
  for (int i = 0; i < 8; ++i){
    c[i] = b2f(c8[i]);
    h[i] = b2f(h8[i]);
    float fc = softplus_(b2f(fc8[i]));
    float gc = softplus_(b2f(gc8[i]));
    float z  = tanh_(b2f(z8[i]));
    fh[i] = softplus_(b2f(fh8[i]));
    dc[i] = -fc*c[i] + gc*z;
    num += dc[i]*c[i];
    den += c[i]*c[i];
  }
#pragma unroll
  for (int s = 1; s < 32; s <<= 1){
    num += __shfl_xor(num, s, 64);
    den += __shfl_xor(den, s, 64);
  }
  const float proj = num / den;

  float4 oa, ob, ha, hb;
  oa.x = dc[0]-proj*c[0]; oa.y = dc[1]-proj*c[1]; oa.z = dc[2]-proj*c[2]; oa.w = dc[3]-proj*c[3];
  ob.x = dc[4]-proj*c[4]; ob.y = dc[5]-proj*c[5]; ob.z = dc[6]-proj*c[6]; ob.w = dc[7]-proj*c[7];
  ha.x = -fh[0]*h[0]; ha.y = -fh[1]*h[1]; ha.z = -fh[2]*h[2]; ha.w = -fh[3]*h[3];
  hb.x = -fh[4]*h[4]; hb.y = -fh[5]*h[5]; hb.z = -fh[6]*h[6]; hb.w = -fh[7]*h[7];
  *(float4*)(orow + q0)       = oa;
  *(float4*)(orow + q0 + 4)   = ob;
  *(float4*)(orow + 256 + q0)     = ha;
  *(float4*)(orow + 256 + q0 + 4) = hb;
}

// ---------------- launch ----------------

extern "C" void kernel_launch(void* const* d_in, const int* in_sizes, int n_in,
                              void* d_out, int out_size, void* d_ws, size_t ws_size,
                              hipStream_t stream) {
  const float* u    = (const float*)d_in[0];
  const int*   src  = (const int*)d_in[1];
  const int*   dst  = (const int*)d_in[2];
  const float* wFc  = (const float*)d_in[4];
  const float* bFc  = (const float*)d_in[5];
  const float* wFh  = (const float*)d_in[6];
  const float* bFh  = (const float*)d_in[7];
  const float* wGc  = (const float*)d_in[8];
  const float* bGc  = (const float*)d_in[9];
  const float* wZ   = (const float*)d_in[10];
  const float* bZ   = (const float*)d_in[11];
  const float* wA   = (const float*)d_in[12];
  const float* bA   = (const float*)d_in[13];
  float* out = (float*)d_out;
  unsigned short* act = (unsigned short*)d_out;   // bf16 activations overlay out

  // ws layout. GEMM A-staging over-reads up to 64 rows past hT/cB/aggT/hB ends —
  // overflow lands in the NEXT allocation (readable garbage, discarded by the
  // r < M_ guard). csr (2.56 MB) ALIASES the hB region: csr is live only
  // fill_direct -> gather; hB is written by gemm<0> strictly after gather.
  char* W = (char*)d_ws;
  unsigned short* hT   = (unsigned short*)(W + 0);           // 20,480,000 B
  unsigned short* cB   = (unsigned short*)(W + 20480000);
  unsigned short* aggT = (unsigned short*)(W + 40960000);
  unsigned short* hB   = (unsigned short*)(W + 61440000);    // 20,480,000 B
  int* csr             = (int*)(W + 61440000);               // 2,560,000 B (aliased)
  unsigned short* WA   = (unsigned short*)(W + 81920000);    // 262,144 B (packed)
  unsigned short* Wall = (unsigned short*)(W + 82182144);    // 1,048,576 B (packed)
  float* biasP   = (float*)(W + 83230720);                   // 4,096 B
  int* cursor    = (int*)(W + 83234816);                     // 20,480 B

  // 6-kernel pipeline: prep -> fill_direct -> gather -> gemm x2 -> epilogue
  prep_kernel<<<12584, 256, 0, stream>>>(u, wA, wFc, wGc, wZ, wFh,
                                         bFc, bGc, bZ, bFh,
                                         cB, hT, WA, Wall, biasP, cursor);
  fill_direct<<<E_/256, 256, 0, stream>>>(src, dst, cursor, csr);
  gather_bn_kernel<<<8*1250, 256, 0, stream>>>(hT, csr, cursor, aggT);

  gemm_tiled<0><<<40*16, 256, 0, stream>>>(hT, aggT, WA, bA, hB);
  gemm_tiled<1><<<40*64, 256, 0, stream>>>(cB, hB, Wall, biasP, act);

  epilogue_kernel<<<M_/8, 256, 0, stream>>>(act, cB, hT, out);
}